// Round 16
// baseline (167.472 us; speedup 1.0000x reference)
//
#include <hip/hip_runtime.h>
#include <hip/hip_bf16.h>
#include <type_traits>

typedef unsigned short u16;
typedef __attribute__((ext_vector_type(2))) float f32x2;
typedef __attribute__((ext_vector_type(4))) float f32x4;
typedef __attribute__((ext_vector_type(8))) short short8;
typedef __attribute__((ext_vector_type(4))) short short4v;
typedef __attribute__((ext_vector_type(8))) __bf16 bf16x8;
typedef __attribute__((ext_vector_type(4))) __bf16 bf16x4;

#define BB 2
#define NN 2048
#define DDIM 1024
#define HH 8
#define QHH 16
#define DHH 64

__device__ __forceinline__ float b2f(u16 v) {
    return __builtin_bit_cast(float, ((unsigned)v) << 16);
}
__device__ __forceinline__ u16 f2b(float f) {
    unsigned u = __builtin_bit_cast(unsigned, f);
    u += 0x7FFFu + ((u >> 16) & 1u);   // RNE
    return (u16)(u >> 16);
}
__device__ __forceinline__ float fastrcp(float x) {
#if __has_builtin(__builtin_amdgcn_rcpf)
    return __builtin_amdgcn_rcpf(x);
#else
    return 1.0f / x;
#endif
}
__device__ __forceinline__ float fastexp2(float x) {
#if __has_builtin(__builtin_amdgcn_exp2f)
    return __builtin_amdgcn_exp2f(x);  // v_exp_f32; NB: __exp2f collides with glibc
#else
    return exp2f(x);
#endif
}
__device__ __forceinline__ f32x2 sp2(float v) { return (f32x2){v, v}; }
__device__ __forceinline__ f32x4 mfma16(short8 a, short8 b, f32x4 c) {
    return __builtin_amdgcn_mfma_f32_16x16x32_bf16(
        __builtin_bit_cast(bf16x8, a), __builtin_bit_cast(bf16x8, b), c, 0, 0, 0);
}
// K=16 MFMA: P^T (C-layout of S^T) is directly the B-operand (verified R9/R10)
#if __has_builtin(__builtin_amdgcn_mfma_f32_16x16x16_bf16)
__device__ __forceinline__ f32x4 mfma_k16(short4v a, short4v b, f32x4 c) {
    return __builtin_amdgcn_mfma_f32_16x16x16_bf16(
        __builtin_bit_cast(bf16x4, a), __builtin_bit_cast(bf16x4, b), c, 0, 0, 0);
}
#else
__device__ __forceinline__ f32x4 mfma_k16(short4v a, short4v b, f32x4 c) {
    return __builtin_amdgcn_mfma_f32_16x16x16bf16_1k(a, b, c, 0, 0, 0);
}
#endif
// async global->LDS, 16B/lane; dst = WAVE-UNIFORM base + lane*16 (m97 pattern)
__device__ __forceinline__ void stage16(const u16* g, u16* l, int lane) {
#if __has_builtin(__builtin_amdgcn_global_load_lds)
    __builtin_amdgcn_global_load_lds(
        (const __attribute__((address_space(1))) unsigned int*)g,
        (__attribute__((address_space(3))) unsigned int*)l, 16, 0, 0);
#else
    *(short8*)(l + lane * 8) = *(const short8*)g;
#endif
}

// ---------------- FUSED pre-pass: rmsnorm (blocks 0..4095) + weight transpose
// (blocks 4096..7167). R25: transpose vectorized (float4 loads, short4 stores). ----------------
__global__ __launch_bounds__(256) void k_pre(const float* __restrict__ tokens,
                                             const float* __restrict__ norm_w,
                                             u16* __restrict__ xb,
                                             const float* __restrict__ Wq,
                                             const float* __restrict__ Wkv,
                                             const float* __restrict__ Wout,
                                             u16* __restrict__ WqT,
                                             u16* __restrict__ WkvT,
                                             u16* __restrict__ WoutT) {
    __shared__ float red[4];
    __shared__ u16 tile[32][36];
    const int bid = blockIdx.x;
    const int tid = threadIdx.x;
    if (bid < 4096) {
        // ---- RMSNorm row ----
        const int row = bid;
        const float* xp = tokens + (size_t)row * DDIM + tid * 4;
        float4 raw = *(const float4*)xp;
        float ss = raw.x * raw.x + raw.y * raw.y + raw.z * raw.z + raw.w * raw.w;
#pragma unroll
        for (int d = 1; d < 64; d <<= 1) ss += __shfl_xor(ss, d);
        if ((tid & 63) == 0) red[tid >> 6] = ss;
        __syncthreads();
        float tot = red[0] + red[1] + red[2] + red[3];
        float r = rsqrtf(tot * (1.0f / 1024.0f) + 1.1920929e-7f);
        float4 wv = *(const float4*)(norm_w + tid * 4);
        ushort4 o;
        o.x = f2b(raw.x * r * wv.x);
        o.y = f2b(raw.y * r * wv.y);
        o.z = f2b(raw.z * r * wv.z);
        o.w = f2b(raw.w * r * wv.w);
        *(ushort4*)(xb + (size_t)row * DDIM + tid * 4) = o;
    } else {
        // ---- weight transpose tile (vectorized) ----
        const int idx = bid - 4096;
        const int z = idx >> 10;
        const int rem = idx & 1023;
        const int by = rem >> 5, bx = rem & 31;
        const float* in = (z == 0) ? Wq : (z == 1) ? Wkv : Wout;
        u16* out = (z == 0) ? WqT : (z == 1) ? WkvT : WoutT;
        const int R = (z == 2) ? 512 : 1024, C = 1024;
        const int br = by * 32;
        if (br >= R) return;
        const int bc = bx * 32;
        const int tx = tid & 7, ty = tid >> 3;   // 8 col-groups x 32 rows
        float4 v = *(const float4*)&in[(size_t)(br + ty) * C + bc + tx * 4];
        tile[ty][tx * 4 + 0] = f2b(v.x);
        tile[ty][tx * 4 + 1] = f2b(v.y);
        tile[ty][tx * 4 + 2] = f2b(v.z);
        tile[ty][tx * 4 + 3] = f2b(v.w);
        __syncthreads();
        u16 o4[4];
#pragma unroll
        for (int j = 0; j < 4; ++j) o4[j] = tile[tx * 4 + j][ty];
        *(short4v*)&out[(size_t)(bc + ty) * R + br + tx * 4] = *(short4v*)o4;
    }
}

// ---------------- GEMM 128x128 BK=64 + FUSED EPILOGUE (R24 WIN): headnorm +
// V-transpose in epilogue; raw qkv never materialized. R21 XCD swizzle +
// R22 BK=64 XOR-swizzled staging. ----------------
__global__ __launch_bounds__(256) void k_gemm128(const u16* __restrict__ A,
                                                 const u16* __restrict__ Bt,
                                                 const float* __restrict__ q_gamma,
                                                 const float* __restrict__ k_gamma,
                                                 u16* __restrict__ qn,
                                                 u16* __restrict__ kn,
                                                 u16* __restrict__ vt,
                                                 int K) {
    __shared__ __attribute__((aligned(16))) u16 As[128 * 64];
    __shared__ __attribute__((aligned(16))) u16 Bs[128 * 64];
    __shared__ __attribute__((aligned(16))) u16 Vst[4 * 64 * 72];   // per-wave transpose slices
    const int tid = threadIdx.x;
    const int lane = tid & 63;
    const int w = tid >> 6;
    const int i = blockIdx.y * 16 + blockIdx.x;   // [0,512)
    const int xcd = i & 7, j = i >> 3;
    const int rm = xcd >> 1, rn = xcd & 1;        // 4x2 region grid
    const int m0 = (rm * 8 + (j >> 3)) * 128;     // 32 m-tiles
    const int n0 = (rn * 8 + (j & 7)) * 128;      // 16 n-tiles
    const int wr = (w >> 1) * 64;
    const int wc = (w & 1) * 64;
    const int lr = lane & 15;
    const int lq = lane >> 4;

    const int ch0 = w * 32;
    const int srow = lane >> 3;              // row within 8-row stage group
    const int sch = (lane ^ srow) & 7;       // pre-swizzled global 16B chunk
    const u16* aSrc = A + (size_t)(m0 + ch0 + srow) * K + sch * 8;
    const u16* bSrc = Bt + (size_t)(n0 + ch0 + srow) * K + sch * 8;
    u16* aDst = As + ch0 * 64;
    u16* bDst = Bs + ch0 * 64;

    f32x4 acc[4][4];
#pragma unroll
    for (int i2 = 0; i2 < 4; i2++)
#pragma unroll
        for (int j2 = 0; j2 < 4; j2++) acc[i2][j2] = (f32x4){0.f, 0.f, 0.f, 0.f};

    for (int k0 = 0; k0 < K; k0 += 64) {
        __syncthreads();
#pragma unroll
        for (int c = 0; c < 4; ++c) {
            stage16(aSrc + (size_t)(c * 8) * K, aDst + c * 8 * 64, lane);
            stage16(bSrc + (size_t)(c * 8) * K, bDst + c * 8 * 64, lane);
        }
        aSrc += 64;
        bSrc += 64;
        __syncthreads();
#pragma unroll
        for (int kk = 0; kk < 2; ++kk) {
            short8 a[4], b[4];
#pragma unroll
            for (int mi = 0; mi < 4; ++mi) {
                const int row = wr + mi * 16 + lr;
                a[mi] = *(const short8*)&As[row * 64 + ((((kk << 2) + lq) ^ (lr & 7)) << 3)];
            }
#pragma unroll
            for (int ni = 0; ni < 4; ++ni) {
                const int row = wc + ni * 16 + lr;
                b[ni] = *(const short8*)&Bs[row * 64 + ((((kk << 2) + lq) ^ (lr & 7)) << 3)];
            }
#pragma unroll
            for (int mi = 0; mi < 4; ++mi)
#pragma unroll
                for (int ni = 0; ni < 4; ++ni) acc[mi][ni] = mfma16(a[mi], b[ni], acc[mi][ni]);
        }
    }

    // ---------------- fused epilogue ----------------
    const int colbase = n0 + wc;   // 64-aligned; region uniform per block
    if (colbase < 1536) {
        const bool isQ = (colbase < 1024);
        const int head = isQ ? (colbase >> 6) : ((colbase - 1024) >> 6);
        const float* gamma = isQ ? q_gamma : k_gamma;
        const float scl = isQ ? 8.0f : 0.16f;     // kn carries softcap 1/50 fold
        u16* outp = isQ ? qn : kn;
        const int HCNT = isQ ? QHH : HH;
        float g[4];
#pragma unroll
        for (int ni = 0; ni < 4; ++ni) g[ni] = gamma[head * 64 + ni * 16 + lr] + 1.0f;
#pragma unroll
        for (int mi = 0; mi < 4; ++mi)
#pragma unroll
            for (int r = 0; r < 4; ++r) {
                float ss = 0.f;
#pragma unroll
                for (int ni = 0; ni < 4; ++ni)
                    ss = fmaf(acc[mi][ni][r], acc[mi][ni][r], ss);
                ss += __shfl_xor(ss, 1);
                ss += __shfl_xor(ss, 2);
                ss += __shfl_xor(ss, 4);
                ss += __shfl_xor(ss, 8);
                const float inv = scl / fmaxf(sqrtf(ss), 1e-12f);
                const int m = m0 + wr + mi * 16 + lq * 4 + r;
                const int b = m >> 11, n = m & 2047;
                u16* rowp = outp + (((size_t)(b * HCNT + head) * NN + n) << 6);
#pragma unroll
                for (int ni = 0; ni < 4; ++ni)
                    rowp[ni * 16 + lr] = f2b(acc[mi][ni][r] * inv * g[ni]);
            }
    } else {
        const int vh = (colbase - 1536) >> 6;
        const int mbase = m0 + wr;             // wave's 64 tokens (within one b)
        const int b = mbase >> 11, nb = mbase & 2047;
        u16* sl = Vst + w * 64 * 72;
#pragma unroll
        for (int mi = 0; mi < 4; ++mi)
#pragma unroll
            for (int ni = 0; ni < 4; ++ni)
#pragma unroll
                for (int r = 0; r < 4; ++r)
                    sl[(mi * 16 + lq * 4 + r) * 72 + ni * 16 + lr] = f2b(acc[mi][ni][r]);
        __syncthreads();   // uniform: whole block is V-region
        u16* vrow = vt + ((size_t)(b * HH + vh) * 64) * NN;
#pragma unroll
        for (int it = 0; it < 8; ++it) {
            int idx = it * 64 + lane;
            int d = idx >> 3, c = idx & 7;
            const int sw = (d >> 3) & 1;       // half-swap for d&8 rows
            u16 tmp[8], o[8];
#pragma unroll
            for (int jj = 0; jj < 8; ++jj) tmp[jj] = sl[(c * 8 + jj) * 72 + d];
#pragma unroll
            for (int jj = 0; jj < 8; ++jj) o[jj] = tmp[jj ^ (sw << 2)];
            *(short8*)&vrow[(size_t)d * NN + nb + c * 8] = *(short8*)o;
        }
    }
}

// ---------------- GEMM 64x128, BK=64 + XCD region swizzle (R23/R25 WINs). ----------------
__global__ __launch_bounds__(256) void k_gemm64f(const u16* __restrict__ A,
                                                 const u16* __restrict__ Bt,
                                                 float* __restrict__ C,
                                                 int M, int Ncols, int K) {
    __shared__ __attribute__((aligned(16))) u16 As[64 * 64];
    __shared__ __attribute__((aligned(16))) u16 Bs[128 * 64];
    const int tid = threadIdx.x;
    const int lane = tid & 63;
    const int w = tid >> 6;
    const int ii = blockIdx.y * 8 + blockIdx.x;   // [0,512)
    const int xcd = ii & 7, jj = ii >> 3;         // 64 blocks per region
    const int m0 = (xcd * 8 + (jj >> 3)) * 64;    // 64 m-tiles: 8 per XCD
    const int n0 = (jj & 7) * 128;                // 8 n-tiles
    const int lr = lane & 15;
    const int lq = lane >> 4;

    const int srow = lane >> 3;
    const int sch = (lane ^ srow) & 7;
    const u16* aSrc = A + (size_t)(m0 + w * 16 + srow) * K + sch * 8;
    const u16* bSrc = Bt + (size_t)(n0 + w * 32 + srow) * K + sch * 8;
    u16* aDst = As + w * 16 * 64;
    u16* bDst = Bs + w * 32 * 64;

    f32x4 acc[8];
#pragma unroll
    for (int i = 0; i < 8; i++) acc[i] = (f32x4){0.f, 0.f, 0.f, 0.f};

    for (int k0 = 0; k0 < K; k0 += 64) {
        __syncthreads();
#pragma unroll
        for (int c = 0; c < 2; ++c)
            stage16(aSrc + (size_t)(c * 8) * K, aDst + c * 8 * 64, lane);
#pragma unroll
        for (int c = 0; c < 4; ++c)
            stage16(bSrc + (size_t)(c * 8) * K, bDst + c * 8 * 64, lane);
        aSrc += 64;
        bSrc += 64;
        __syncthreads();
#pragma unroll
        for (int kk = 0; kk < 2; ++kk) {
            const int chunk = ((kk << 2) + lq) ^ (lr & 7);
            short8 a = *(const short8*)&As[(w * 16 + lr) * 64 + (chunk << 3)];
#pragma unroll
            for (int nt = 0; nt < 8; ++nt) {
                short8 b = *(const short8*)&Bs[(nt * 16 + lr) * 64 + (chunk << 3)];
                acc[nt] = mfma16(a, b, acc[nt]);
            }
        }
    }
#pragma unroll
    for (int nt = 0; nt < 8; ++nt)
#pragma unroll
        for (int r = 0; r < 4; ++r) {
            int row = m0 + w * 16 + lq * 4 + r;
            int col = n0 + nt * 16 + lr;
            C[(size_t)row * Ncols + col] = acc[nt][r];
        }
}

// ---------------- flash attention v18 (R26): 4-WAY SPLIT-J.
// Every strip z split s in [0,4): jb=(ntile*s)>>2, je=(ntile*(s+1))>>2.
// Grid 32x128 = 4096 blocks -> 16 dispatched/CU, 8 resident (wave cap) = FULL
// 32 waves/CU; max block = 8 tiles (was 16). Masked diag tile always in s=3
// (je=ntile, ntl>=1 for ntile>=1). Empty splits write zero O/L (combiner-safe).
// Keeps: single-buffer 16KB LDS, conflict-free vf, setprio, packed-poly softmax. ----------------
__global__ __launch_bounds__(256) void k_attn(const u16* __restrict__ qn,
                                              const u16* __restrict__ kn,
                                              const u16* __restrict__ vt,
                                              u16* __restrict__ OT,
                                              float* __restrict__ Lp) {
    const int bq = blockIdx.x;  // b*16+qh
    const int b = bq >> 4, qh = bq & 15;
    const int h = qh >> 1;
    const int tid = threadIdx.x;
    const int lane = tid & 63, w = tid >> 6;
    const int lr = lane & 15, lq = lane >> 4;
    const int y = blockIdx.y;
    const int z = 31 - (y >> 2);     // LPT: heaviest strips first
    const int s = y & 3;             // j-split quarter
    const int ntile = z + 1;
    const int jb = (ntile * s) >> 2;
    const int je = (ntile * (s + 1)) >> 2;
    const int ntl = je - jb;
    const int i0 = z * 64 + w * 16;
    const int irow = i0 + lr;

    const u16* Qp = qn + (size_t)(b * QHH + qh) * NN * 64;
    const u16* Kp = kn + (size_t)(b * HH + h) * NN * 64;
    const u16* Vp = vt + (size_t)(b * HH + h) * 64 * NN;
    u16* Op = OT + (size_t)s * (BB * QHH * NN * 64) + (size_t)bq * NN * 64;  // [s][bq][n][d]
    float* Lsel = Lp + (size_t)s * (BB * QHH * NN) + (size_t)bq * NN;        // [s][bq][n]

    __shared__ __attribute__((aligned(16))) u16 Ks[64 * 64];
    __shared__ __attribute__((aligned(16))) u16 Vs[64 * 64];

    short8 qf0 = *(const short8*)&Qp[(size_t)(i0 + lr) * 64 + lq * 8];
    short8 qf1 = *(const short8*)&Qp[(size_t)(i0 + lr) * 64 + 32 + lq * 8];

    f32x4 of[4];
#pragma unroll
    for (int dt = 0; dt < 4; ++dt) of[dt] = (f32x4){0.f, 0.f, 0.f, 0.f};
    f32x2 ls = {0.f, 0.f};

    const int srow = lane >> 3;
    const int sch = (lane ^ srow) & 7;
    const int rA = w * 16, rB = w * 16 + 8;

    // incremental staging pointers, pre-offset to tile jb
    const u16* kSrcA = Kp + (size_t)jb * 4096 + (size_t)(rA + srow) * 64 + sch * 8;
    const u16* kSrcB = Kp + (size_t)jb * 4096 + (size_t)(rB + srow) * 64 + sch * 8;
    const u16* vSrcA = Vp + (size_t)(rA + srow) * NN + jb * 64 + sch * 8;
    const u16* vSrcB = Vp + (size_t)(rB + srow) * NN + jb * 64 + sch * 8;

    auto stageKV = [&]() {
        stage16(kSrcA, &Ks[rA * 64], lane);
        stage16(kSrcB, &Ks[rB * 64], lane);
        stage16(vSrcA, &Vs[rA * 64], lane);
        stage16(vSrcB, &Vs[rB * 64], lane);
        kSrcA += 64 * 64;
        kSrcB += 64 * 64;
        vSrcA += 64;
        vSrcB += 64;
    };

    // softmax on one 4-elem score fragment: x=sim/50 pre-folded; p=exp2(G(x^2)*x - c)
    auto smax = [&](f32x4 sc, int lim, bool masked) -> short4v {
        f32x2 xa = {sc[0], sc[1]};
        f32x2 xb = {sc[2], sc[3]};
        f32x2 ya = xa * xa;
        f32x2 yb = xb * xb;
        f32x2 Ga = __builtin_elementwise_fma(ya, __builtin_elementwise_fma(ya,
                       __builtin_elementwise_fma(ya, __builtin_elementwise_fma(ya,
                           sp2(0.04705711f), sp2(-0.32327190f)), sp2(1.11500760f)),
                       sp2(-2.98719110f)), sp2(9.01599730f));
        f32x2 Gb = __builtin_elementwise_fma(yb, __builtin_elementwise_fma(yb,
                       __builtin_elementwise_fma(yb, __builtin_elementwise_fma(yb,
                           sp2(0.04705711f), sp2(-0.32327190f)), sp2(1.11500760f)),
                       sp2(-2.98719110f)), sp2(9.01599730f));
        f32x2 aa = __builtin_elementwise_fma(xa, Ga, sp2(-9.0168440f));
        f32x2 ab = __builtin_elementwise_fma(xb, Gb, sp2(-9.0168440f));
        float p0 = fastexp2(aa.x);
        float p1 = fastexp2(aa.y);
        float p2 = fastexp2(ab.x);
        float p3 = fastexp2(ab.y);
        if (masked) {
            p0 = (0 <= lim) ? p0 : 0.0f;
            p1 = (1 <= lim) ? p1 : 0.0f;
            p2 = (2 <= lim) ? p2 : 0.0f;
            p3 = (3 <= lim) ? p3 : 0.0f;
        }
        ls += (f32x2){p0, p1};
        ls += (f32x2){p2, p3};
        bf16x4 pb;
        pb[0] = (__bf16)p0;
        pb[1] = (__bf16)p1;
        pb[2] = (__bf16)p2;
        pb[3] = (__bf16)p3;
        return __builtin_bit_cast(short4v, pb);
    };

    auto tile = [&](int jt) {
        const int j0 = jt << 6;
        const u16* kb = &Ks[0];
        const u16* vb = &Vs[0];
        f32x4 sc[4];
        __builtin_amdgcn_s_setprio(1);
#pragma unroll
        for (int ct = 0; ct < 4; ++ct) {
            const int r = ct * 16 + lr;
            short8 kf0 = *(const short8*)&kb[r * 64 + ((lq ^ (lr & 7)) << 3)];
            short8 kf1 = *(const short8*)&kb[r * 64 + (((4 + lq) ^ (lr & 7)) << 3)];
            f32x4 t = (f32x4){0.f, 0.f, 0.f, 0.f};
            t = mfma16(kf0, qf0, t);
            t = mfma16(kf1, qf1, t);
            sc[ct] = t;
        }
        __builtin_amdgcn_s_setprio(0);
        const bool masked = (jt == ntile - 1);
        short4v pk[4];
#pragma unroll
        for (int ct = 0; ct < 4; ++ct) {
            const int lim = irow - (j0 + ct * 16 + lq * 4);
            pk[ct] = smax(sc[ct], lim, masked);
        }
        __builtin_amdgcn_s_setprio(1);
#pragma unroll
        for (int dt = 0; dt < 4; ++dt) {
            const int d = dt * 16 + lr;
#pragma unroll
            for (int ct = 0; ct < 4; ++ct) {
                short4v vf = *(const short4v*)
                    &vb[d * 64 + ((((ct << 1) + (lq >> 1)) ^ (lr & 7)) << 3) +
                        (((lq ^ (lr >> 3)) & 1) << 2)];
                of[dt] = mfma_k16(vf, pk[ct], of[dt]);
            }
        }
        __builtin_amdgcn_s_setprio(0);
    };

    for (int t = 0; t < ntl; ++t) {
        __syncthreads();          // WAR: prior tile's LDS reads complete
        stageKV();
        __syncthreads();          // staged data visible
        tile(jb + t);
    }

    float l = ls.x + ls.y;
    l += __shfl_xor(l, 16);
    l += __shfl_xor(l, 32);
    // write UNNORMALIZED partial O (bf16, n-major) + partial l (one per row)
#pragma unroll
    for (int dt = 0; dt < 4; ++dt) {
        u16 o[4];
#pragma unroll
        for (int r = 0; r < 4; ++r) o[r] = f2b(of[dt][r]);
        *(ushort4*)&Op[(size_t)irow * 64 + dt * 16 + lq * 4] = *(ushort4*)o;
    }
    if (lq == 0) Lsel[irow] = l;
}

// ---------------- combine 4 splits + groups (n-major partials):
// AO[b,n,hh*64+d] = (Σ_s Oa_s)/(Σ_s la_s) + (Σ_s Ob_s)/(Σ_s lb_s)
// grid-stride x2, fully coalesced, no LDS ----------------
__global__ __launch_bounds__(256) void k_gsum(const u16* __restrict__ O,
                                              const float* __restrict__ Lp,
                                              u16* __restrict__ AO) {
    const size_t SOFF = (size_t)BB * QHH * NN * 64;   // per-split O stride (u16)
    const size_t LOFF = (size_t)BB * QHH * NN;        // per-split L stride (f32)
#pragma unroll
    for (int it = 0; it < 2; ++it) {
        const int idx = blockIdx.x * 256 + threadIdx.x + it * 131072;  // 8B chunk id
        const int c8 = idx & 63;
        const int n = (idx >> 6) & 2047;
        const int b = idx >> 17;
        const int hh = c8 >> 3;
        const int ch = c8 & 7;
        const int q0 = b * QHH + 2 * hh, q1 = q0 + 1;
        float l0 = 0.f, l1 = 0.f;
        float s0[8], s1[8];
#pragma unroll
        for (int jx = 0; jx < 8; ++jx) { s0[jx] = 0.f; s1[jx] = 0.f; }
#pragma unroll
        for (int sp = 0; sp < 4; ++sp) {
            const u16* a0 = O + sp * SOFF + ((size_t)q0 * NN + n) * 64 + ch * 8;
            const u16* a1 = O + sp * SOFF + ((size_t)q1 * NN + n) * 64 + ch * 8;
            short8 v0 = *(const short8*)a0;
            short8 v1 = *(const short8*)a1;
#pragma unroll
            for (int jx = 0; jx < 8; ++jx) {
                s0[jx] += b2f((u16)v0[jx]);
                s1[jx] += b2f((u16)v1[jx]);
            }
            l0 += Lp[sp * LOFF + (size_t)q0 * NN + n];
            l1 += Lp[sp * LOFF + (size_t)q1 * NN + n];
        }
        const float inv0 = fastrcp(l0);
        const float inv1 = fastrcp(l1);
        u16 o[8];
#pragma unroll
        for (int jx = 0; jx < 8; ++jx)
            o[jx] = f2b(s0[jx] * inv0 + s1[jx] * inv1);
        *(short8*)&AO[((size_t)(b * NN + n)) * 512 + c8 * 8] = *(short8*)o;
    }
}

extern "C" void kernel_launch(void* const* d_in, const int* in_sizes, int n_in,
                              void* d_out, int out_size, void* d_ws, size_t ws_size,
                              hipStream_t stream) {
    const float* tokens = (const float*)d_in[0];
    const float* norm_w = (const float*)d_in[1];
    const float* Wq = (const float*)d_in[2];
    const float* Wkv = (const float*)d_in[3];
    const float* Wout = (const float*)d_in[4];
    const float* q_gamma = (const float*)d_in[5];
    const float* k_gamma = (const float*)d_in[6];
    float* out = (float*)d_out;

    char* ws = (char*)d_ws;
    u16* xb = (u16*)(ws + 0);             // 8 MB  [4096,1024]
    u16* WqT = (u16*)(ws + 8388608);      // 2 MB  } adjacent => fused Bt [2048][1024]
    u16* WkvT = (u16*)(ws + 10485760);    // 2 MB  }
    u16* WoutT = (u16*)(ws + 12582912);   // 1 MB
    u16* Opart = (u16*)(ws + 13631488);   // 32 MB: 4 splits x 8 MB -> ends 47185920
    u16* kn = (u16*)(ws + 47185920);      // 4 MB
    u16* vtb = (u16*)(ws + 51380224);     // 4 MB
    u16* qn = (u16*)(ws + 55574528);      // 8 MB -> ends 63963136
    float* Lpart = (float*)(ws + 8388608);  // 1 MB in WqT/WkvT region (dead after gemm128)
    u16* AO = kn;                         // 4 MB: kn dead after attn; AO written by gsum

    k_pre<<<7168, 256, 0, stream>>>(tokens, norm_w, xb, Wq, Wkv, Wout, WqT, WkvT, WoutT);
    // fused QKV GEMM + headnorm/V-transpose epilogue
    k_gemm128<<<dim3(16, 32), 256, 0, stream>>>(xb, WqT, q_gamma, k_gamma, qn, kn, vtb, 1024);
    k_attn<<<dim3(32, 128), 256, 0, stream>>>(qn, kn, vtb, Opart, Lpart);
    k_gsum<<<512, 256, 0, stream>>>(Opart, Lpart, AO);
    k_gemm64f<<<dim3(8, 64), 256, 0, stream>>>(AO, WoutT, out, 4096, 1024, 512);
}

// Round 17
// 163.911 us; speedup vs baseline: 1.0217x; 1.0217x over previous
//
#include <hip/hip_runtime.h>
#include <hip/hip_bf16.h>
#include <type_traits>

typedef unsigned short u16;
typedef __attribute__((ext_vector_type(2))) float f32x2;
typedef __attribute__((ext_vector_type(4))) float f32x4;
typedef __attribute__((ext_vector_type(8))) short short8;
typedef __attribute__((ext_vector_type(4))) short short4v;
typedef __attribute__((ext_vector_type(8))) __bf16 bf16x8;
typedef __attribute__((ext_vector_type(4))) __bf16 bf16x4;

#define BB 2
#define NN 2048
#define DDIM 1024
#define HH 8
#define QHH 16
#define DHH 64

__device__ __forceinline__ float b2f(u16 v) {
    return __builtin_bit_cast(float, ((unsigned)v) << 16);
}
__device__ __forceinline__ u16 f2b(float f) {
    unsigned u = __builtin_bit_cast(unsigned, f);
    u += 0x7FFFu + ((u >> 16) & 1u);   // RNE
    return (u16)(u >> 16);
}
__device__ __forceinline__ float fastrcp(float x) {
#if __has_builtin(__builtin_amdgcn_rcpf)
    return __builtin_amdgcn_rcpf(x);
#else
    return 1.0f / x;
#endif
}
__device__ __forceinline__ float fastexp2(float x) {
#if __has_builtin(__builtin_amdgcn_exp2f)
    return __builtin_amdgcn_exp2f(x);  // v_exp_f32; NB: __exp2f collides with glibc
#else
    return exp2f(x);
#endif
}
__device__ __forceinline__ f32x2 sp2(float v) { return (f32x2){v, v}; }
__device__ __forceinline__ f32x4 mfma16(short8 a, short8 b, f32x4 c) {
    return __builtin_amdgcn_mfma_f32_16x16x32_bf16(
        __builtin_bit_cast(bf16x8, a), __builtin_bit_cast(bf16x8, b), c, 0, 0, 0);
}
// K=16 MFMA: P^T (C-layout of S^T) is directly the B-operand (verified R9/R10)
#if __has_builtin(__builtin_amdgcn_mfma_f32_16x16x16_bf16)
__device__ __forceinline__ f32x4 mfma_k16(short4v a, short4v b, f32x4 c) {
    return __builtin_amdgcn_mfma_f32_16x16x16_bf16(
        __builtin_bit_cast(bf16x4, a), __builtin_bit_cast(bf16x4, b), c, 0, 0, 0);
}
#else
__device__ __forceinline__ f32x4 mfma_k16(short4v a, short4v b, f32x4 c) {
    return __builtin_amdgcn_mfma_f32_16x16x16bf16_1k(a, b, c, 0, 0, 0);
}
#endif
// async global->LDS, 16B/lane; dst = WAVE-UNIFORM base + lane*16 (m97 pattern)
__device__ __forceinline__ void stage16(const u16* g, u16* l, int lane) {
#if __has_builtin(__builtin_amdgcn_global_load_lds)
    __builtin_amdgcn_global_load_lds(
        (const __attribute__((address_space(1))) unsigned int*)g,
        (__attribute__((address_space(3))) unsigned int*)l, 16, 0, 0);
#else
    *(short8*)(l + lane * 8) = *(const short8*)g;
#endif
}

// ---------------- FUSED pre-pass: rmsnorm (blocks 0..4095) + weight transpose
// (blocks 4096..7167). R25: transpose vectorized (float4 loads, short4 stores). ----------------
__global__ __launch_bounds__(256) void k_pre(const float* __restrict__ tokens,
                                             const float* __restrict__ norm_w,
                                             u16* __restrict__ xb,
                                             const float* __restrict__ Wq,
                                             const float* __restrict__ Wkv,
                                             const float* __restrict__ Wout,
                                             u16* __restrict__ WqT,
                                             u16* __restrict__ WkvT,
                                             u16* __restrict__ WoutT) {
    __shared__ float red[4];
    __shared__ u16 tile[32][36];
    const int bid = blockIdx.x;
    const int tid = threadIdx.x;
    if (bid < 4096) {
        // ---- RMSNorm row ----
        const int row = bid;
        const float* xp = tokens + (size_t)row * DDIM + tid * 4;
        float4 raw = *(const float4*)xp;
        float ss = raw.x * raw.x + raw.y * raw.y + raw.z * raw.z + raw.w * raw.w;
#pragma unroll
        for (int d = 1; d < 64; d <<= 1) ss += __shfl_xor(ss, d);
        if ((tid & 63) == 0) red[tid >> 6] = ss;
        __syncthreads();
        float tot = red[0] + red[1] + red[2] + red[3];
        float r = rsqrtf(tot * (1.0f / 1024.0f) + 1.1920929e-7f);
        float4 wv = *(const float4*)(norm_w + tid * 4);
        ushort4 o;
        o.x = f2b(raw.x * r * wv.x);
        o.y = f2b(raw.y * r * wv.y);
        o.z = f2b(raw.z * r * wv.z);
        o.w = f2b(raw.w * r * wv.w);
        *(ushort4*)(xb + (size_t)row * DDIM + tid * 4) = o;
    } else {
        // ---- weight transpose tile (vectorized) ----
        const int idx = bid - 4096;
        const int z = idx >> 10;
        const int rem = idx & 1023;
        const int by = rem >> 5, bx = rem & 31;
        const float* in = (z == 0) ? Wq : (z == 1) ? Wkv : Wout;
        u16* out = (z == 0) ? WqT : (z == 1) ? WkvT : WoutT;
        const int R = (z == 2) ? 512 : 1024, C = 1024;
        const int br = by * 32;
        if (br >= R) return;
        const int bc = bx * 32;
        const int tx = tid & 7, ty = tid >> 3;   // 8 col-groups x 32 rows
        float4 v = *(const float4*)&in[(size_t)(br + ty) * C + bc + tx * 4];
        tile[ty][tx * 4 + 0] = f2b(v.x);
        tile[ty][tx * 4 + 1] = f2b(v.y);
        tile[ty][tx * 4 + 2] = f2b(v.z);
        tile[ty][tx * 4 + 3] = f2b(v.w);
        __syncthreads();
        u16 o4[4];
#pragma unroll
        for (int j = 0; j < 4; ++j) o4[j] = tile[tx * 4 + j][ty];
        *(short4v*)&out[(size_t)(bc + ty) * R + br + tx * 4] = *(short4v*)o4;
    }
}

// ---------------- GEMM 128x128 BK=64 + FUSED EPILOGUE (R24 WIN): headnorm +
// V-transpose in epilogue; raw qkv never materialized. R21 XCD swizzle +
// R22 BK=64 XOR-swizzled staging. ----------------
__global__ __launch_bounds__(256) void k_gemm128(const u16* __restrict__ A,
                                                 const u16* __restrict__ Bt,
                                                 const float* __restrict__ q_gamma,
                                                 const float* __restrict__ k_gamma,
                                                 u16* __restrict__ qn,
                                                 u16* __restrict__ kn,
                                                 u16* __restrict__ vt,
                                                 int K) {
    __shared__ __attribute__((aligned(16))) u16 As[128 * 64];
    __shared__ __attribute__((aligned(16))) u16 Bs[128 * 64];
    __shared__ __attribute__((aligned(16))) u16 Vst[4 * 64 * 72];   // per-wave transpose slices
    const int tid = threadIdx.x;
    const int lane = tid & 63;
    const int w = tid >> 6;
    const int i = blockIdx.y * 16 + blockIdx.x;   // [0,512)
    const int xcd = i & 7, j = i >> 3;
    const int rm = xcd >> 1, rn = xcd & 1;        // 4x2 region grid
    const int m0 = (rm * 8 + (j >> 3)) * 128;     // 32 m-tiles
    const int n0 = (rn * 8 + (j & 7)) * 128;      // 16 n-tiles
    const int wr = (w >> 1) * 64;
    const int wc = (w & 1) * 64;
    const int lr = lane & 15;
    const int lq = lane >> 4;

    const int ch0 = w * 32;
    const int srow = lane >> 3;              // row within 8-row stage group
    const int sch = (lane ^ srow) & 7;       // pre-swizzled global 16B chunk
    const u16* aSrc = A + (size_t)(m0 + ch0 + srow) * K + sch * 8;
    const u16* bSrc = Bt + (size_t)(n0 + ch0 + srow) * K + sch * 8;
    u16* aDst = As + ch0 * 64;
    u16* bDst = Bs + ch0 * 64;

    f32x4 acc[4][4];
#pragma unroll
    for (int i2 = 0; i2 < 4; i2++)
#pragma unroll
        for (int j2 = 0; j2 < 4; j2++) acc[i2][j2] = (f32x4){0.f, 0.f, 0.f, 0.f};

    for (int k0 = 0; k0 < K; k0 += 64) {
        __syncthreads();
#pragma unroll
        for (int c = 0; c < 4; ++c) {
            stage16(aSrc + (size_t)(c * 8) * K, aDst + c * 8 * 64, lane);
            stage16(bSrc + (size_t)(c * 8) * K, bDst + c * 8 * 64, lane);
        }
        aSrc += 64;
        bSrc += 64;
        __syncthreads();
#pragma unroll
        for (int kk = 0; kk < 2; ++kk) {
            short8 a[4], b[4];
#pragma unroll
            for (int mi = 0; mi < 4; ++mi) {
                const int row = wr + mi * 16 + lr;
                a[mi] = *(const short8*)&As[row * 64 + ((((kk << 2) + lq) ^ (lr & 7)) << 3)];
            }
#pragma unroll
            for (int ni = 0; ni < 4; ++ni) {
                const int row = wc + ni * 16 + lr;
                b[ni] = *(const short8*)&Bs[row * 64 + ((((kk << 2) + lq) ^ (lr & 7)) << 3)];
            }
#pragma unroll
            for (int mi = 0; mi < 4; ++mi)
#pragma unroll
                for (int ni = 0; ni < 4; ++ni) acc[mi][ni] = mfma16(a[mi], b[ni], acc[mi][ni]);
        }
    }

    // ---------------- fused epilogue ----------------
    const int colbase = n0 + wc;   // 64-aligned; region uniform per block
    if (colbase < 1536) {
        const bool isQ = (colbase < 1024);
        const int head = isQ ? (colbase >> 6) : ((colbase - 1024) >> 6);
        const float* gamma = isQ ? q_gamma : k_gamma;
        const float scl = isQ ? 8.0f : 0.16f;     // kn carries softcap 1/50 fold
        u16* outp = isQ ? qn : kn;
        const int HCNT = isQ ? QHH : HH;
        float g[4];
#pragma unroll
        for (int ni = 0; ni < 4; ++ni) g[ni] = gamma[head * 64 + ni * 16 + lr] + 1.0f;
#pragma unroll
        for (int mi = 0; mi < 4; ++mi)
#pragma unroll
            for (int r = 0; r < 4; ++r) {
                float ss = 0.f;
#pragma unroll
                for (int ni = 0; ni < 4; ++ni)
                    ss = fmaf(acc[mi][ni][r], acc[mi][ni][r], ss);
                ss += __shfl_xor(ss, 1);
                ss += __shfl_xor(ss, 2);
                ss += __shfl_xor(ss, 4);
                ss += __shfl_xor(ss, 8);
                const float inv = scl / fmaxf(sqrtf(ss), 1e-12f);
                const int m = m0 + wr + mi * 16 + lq * 4 + r;
                const int b = m >> 11, n = m & 2047;
                u16* rowp = outp + (((size_t)(b * HCNT + head) * NN + n) << 6);
#pragma unroll
                for (int ni = 0; ni < 4; ++ni)
                    rowp[ni * 16 + lr] = f2b(acc[mi][ni][r] * inv * g[ni]);
            }
    } else {
        const int vh = (colbase - 1536) >> 6;
        const int mbase = m0 + wr;             // wave's 64 tokens (within one b)
        const int b = mbase >> 11, nb = mbase & 2047;
        u16* sl = Vst + w * 64 * 72;
#pragma unroll
        for (int mi = 0; mi < 4; ++mi)
#pragma unroll
            for (int ni = 0; ni < 4; ++ni)
#pragma unroll
                for (int r = 0; r < 4; ++r)
                    sl[(mi * 16 + lq * 4 + r) * 72 + ni * 16 + lr] = f2b(acc[mi][ni][r]);
        __syncthreads();   // uniform: whole block is V-region
        u16* vrow = vt + ((size_t)(b * HH + vh) * 64) * NN;
#pragma unroll
        for (int it = 0; it < 8; ++it) {
            int idx = it * 64 + lane;
            int d = idx >> 3, c = idx & 7;
            const int sw = (d >> 3) & 1;       // half-swap for d&8 rows
            u16 tmp[8], o[8];
#pragma unroll
            for (int jj = 0; jj < 8; ++jj) tmp[jj] = sl[(c * 8 + jj) * 72 + d];
#pragma unroll
            for (int jj = 0; jj < 8; ++jj) o[jj] = tmp[jj ^ (sw << 2)];
            *(short8*)&vrow[(size_t)d * NN + nb + c * 8] = *(short8*)o;
        }
    }
}

// ---------------- GEMM 64x128, BK=64 + XCD region swizzle (R23/R25 WINs). ----------------
__global__ __launch_bounds__(256) void k_gemm64f(const u16* __restrict__ A,
                                                 const u16* __restrict__ Bt,
                                                 float* __restrict__ C,
                                                 int M, int Ncols, int K) {
    __shared__ __attribute__((aligned(16))) u16 As[64 * 64];
    __shared__ __attribute__((aligned(16))) u16 Bs[128 * 64];
    const int tid = threadIdx.x;
    const int lane = tid & 63;
    const int w = tid >> 6;
    const int ii = blockIdx.y * 8 + blockIdx.x;   // [0,512)
    const int xcd = ii & 7, jj = ii >> 3;         // 64 blocks per region
    const int m0 = (xcd * 8 + (jj >> 3)) * 64;    // 64 m-tiles: 8 per XCD
    const int n0 = (jj & 7) * 128;                // 8 n-tiles
    const int lr = lane & 15;
    const int lq = lane >> 4;

    const int srow = lane >> 3;
    const int sch = (lane ^ srow) & 7;
    const u16* aSrc = A + (size_t)(m0 + w * 16 + srow) * K + sch * 8;
    const u16* bSrc = Bt + (size_t)(n0 + w * 32 + srow) * K + sch * 8;
    u16* aDst = As + w * 16 * 64;
    u16* bDst = Bs + w * 32 * 64;

    f32x4 acc[8];
#pragma unroll
    for (int i = 0; i < 8; i++) acc[i] = (f32x4){0.f, 0.f, 0.f, 0.f};

    for (int k0 = 0; k0 < K; k0 += 64) {
        __syncthreads();
#pragma unroll
        for (int c = 0; c < 2; ++c)
            stage16(aSrc + (size_t)(c * 8) * K, aDst + c * 8 * 64, lane);
#pragma unroll
        for (int c = 0; c < 4; ++c)
            stage16(bSrc + (size_t)(c * 8) * K, bDst + c * 8 * 64, lane);
        aSrc += 64;
        bSrc += 64;
        __syncthreads();
#pragma unroll
        for (int kk = 0; kk < 2; ++kk) {
            const int chunk = ((kk << 2) + lq) ^ (lr & 7);
            short8 a = *(const short8*)&As[(w * 16 + lr) * 64 + (chunk << 3)];
#pragma unroll
            for (int nt = 0; nt < 8; ++nt) {
                short8 b = *(const short8*)&Bs[(nt * 16 + lr) * 64 + (chunk << 3)];
                acc[nt] = mfma16(a, b, acc[nt]);
            }
        }
    }
#pragma unroll
    for (int nt = 0; nt < 8; ++nt)
#pragma unroll
        for (int r = 0; r < 4; ++r) {
            int row = m0 + w * 16 + lq * 4 + r;
            int col = n0 + nt * 16 + lr;
            C[(size_t)row * Ncols + col] = acc[nt][r];
        }
}

// ---------------- flash attention v17 (R19 structure): 2-way split-j +
// single-buffer 16KB LDS, conflict-free vf reads, setprio, packed-poly softmax,
// n-major unnormalized partials + L. (R26's 4-way split reverted: occupancy
// stuck at ~34% regardless of grid — latency not TLP-maskable; extra partial
// traffic was pure cost.) ----------------
__global__ __launch_bounds__(256) void k_attn(const u16* __restrict__ qn,
                                              const u16* __restrict__ kn,
                                              const u16* __restrict__ vt,
                                              u16* __restrict__ OT,
                                              float* __restrict__ Lp) {
    const int bq = blockIdx.x;  // b*16+qh
    const int b = bq >> 4, qh = bq & 15;
    const int h = qh >> 1;
    const int tid = threadIdx.x;
    const int lane = tid & 63, w = tid >> 6;
    const int lr = lane & 15, lq = lane >> 4;
    const int y = blockIdx.y;
    const int z = 31 - (y >> 1);     // LPT: heaviest strips first
    const int s = y & 1;             // j-split half
    const int ntile = z + 1;
    const int jmid = (ntile + 1) >> 1;
    const int jb = s ? jmid : 0;
    const int je = s ? ntile : jmid;
    const int ntl = je - jb;
    const int i0 = z * 64 + w * 16;
    const int irow = i0 + lr;

    const u16* Qp = qn + (size_t)(b * QHH + qh) * NN * 64;
    const u16* Kp = kn + (size_t)(b * HH + h) * NN * 64;
    const u16* Vp = vt + (size_t)(b * HH + h) * 64 * NN;
    u16* Op = OT + (size_t)s * (BB * QHH * NN * 64) + (size_t)bq * NN * 64;  // [s][bq][n][d]
    float* Lsel = Lp + (size_t)s * (BB * QHH * NN) + (size_t)bq * NN;        // [s][bq][n]

    __shared__ __attribute__((aligned(16))) u16 Ks[64 * 64];
    __shared__ __attribute__((aligned(16))) u16 Vs[64 * 64];

    short8 qf0 = *(const short8*)&Qp[(size_t)(i0 + lr) * 64 + lq * 8];
    short8 qf1 = *(const short8*)&Qp[(size_t)(i0 + lr) * 64 + 32 + lq * 8];

    f32x4 of[4];
#pragma unroll
    for (int dt = 0; dt < 4; ++dt) of[dt] = (f32x4){0.f, 0.f, 0.f, 0.f};
    f32x2 ls = {0.f, 0.f};

    const int srow = lane >> 3;
    const int sch = (lane ^ srow) & 7;
    const int rA = w * 16, rB = w * 16 + 8;

    // incremental staging pointers, pre-offset to tile jb
    const u16* kSrcA = Kp + (size_t)jb * 4096 + (size_t)(rA + srow) * 64 + sch * 8;
    const u16* kSrcB = Kp + (size_t)jb * 4096 + (size_t)(rB + srow) * 64 + sch * 8;
    const u16* vSrcA = Vp + (size_t)(rA + srow) * NN + jb * 64 + sch * 8;
    const u16* vSrcB = Vp + (size_t)(rB + srow) * NN + jb * 64 + sch * 8;

    auto stageKV = [&]() {
        stage16(kSrcA, &Ks[rA * 64], lane);
        stage16(kSrcB, &Ks[rB * 64], lane);
        stage16(vSrcA, &Vs[rA * 64], lane);
        stage16(vSrcB, &Vs[rB * 64], lane);
        kSrcA += 64 * 64;
        kSrcB += 64 * 64;
        vSrcA += 64;
        vSrcB += 64;
    };

    // softmax on one 4-elem score fragment: x=sim/50 pre-folded; p=exp2(G(x^2)*x - c)
    auto smax = [&](f32x4 sc, int lim, bool masked) -> short4v {
        f32x2 xa = {sc[0], sc[1]};
        f32x2 xb = {sc[2], sc[3]};
        f32x2 ya = xa * xa;
        f32x2 yb = xb * xb;
        f32x2 Ga = __builtin_elementwise_fma(ya, __builtin_elementwise_fma(ya,
                       __builtin_elementwise_fma(ya, __builtin_elementwise_fma(ya,
                           sp2(0.04705711f), sp2(-0.32327190f)), sp2(1.11500760f)),
                       sp2(-2.98719110f)), sp2(9.01599730f));
        f32x2 Gb = __builtin_elementwise_fma(yb, __builtin_elementwise_fma(yb,
                       __builtin_elementwise_fma(yb, __builtin_elementwise_fma(yb,
                           sp2(0.04705711f), sp2(-0.32327190f)), sp2(1.11500760f)),
                       sp2(-2.98719110f)), sp2(9.01599730f));
        f32x2 aa = __builtin_elementwise_fma(xa, Ga, sp2(-9.0168440f));
        f32x2 ab = __builtin_elementwise_fma(xb, Gb, sp2(-9.0168440f));
        float p0 = fastexp2(aa.x);
        float p1 = fastexp2(aa.y);
        float p2 = fastexp2(ab.x);
        float p3 = fastexp2(ab.y);
        if (masked) {
            p0 = (0 <= lim) ? p0 : 0.0f;
            p1 = (1 <= lim) ? p1 : 0.0f;
            p2 = (2 <= lim) ? p2 : 0.0f;
            p3 = (3 <= lim) ? p3 : 0.0f;
        }
        ls += (f32x2){p0, p1};
        ls += (f32x2){p2, p3};
        bf16x4 pb;
        pb[0] = (__bf16)p0;
        pb[1] = (__bf16)p1;
        pb[2] = (__bf16)p2;
        pb[3] = (__bf16)p3;
        return __builtin_bit_cast(short4v, pb);
    };

    auto tile = [&](int jt) {
        const int j0 = jt << 6;
        const u16* kb = &Ks[0];
        const u16* vb = &Vs[0];
        f32x4 sc[4];
        __builtin_amdgcn_s_setprio(1);
#pragma unroll
        for (int ct = 0; ct < 4; ++ct) {
            const int r = ct * 16 + lr;
            short8 kf0 = *(const short8*)&kb[r * 64 + ((lq ^ (lr & 7)) << 3)];
            short8 kf1 = *(const short8*)&kb[r * 64 + (((4 + lq) ^ (lr & 7)) << 3)];
            f32x4 t = (f32x4){0.f, 0.f, 0.f, 0.f};
            t = mfma16(kf0, qf0, t);
            t = mfma16(kf1, qf1, t);
            sc[ct] = t;
        }
        __builtin_amdgcn_s_setprio(0);
        const bool masked = (jt == ntile - 1);
        short4v pk[4];
#pragma unroll
        for (int ct = 0; ct < 4; ++ct) {
            const int lim = irow - (j0 + ct * 16 + lq * 4);
            pk[ct] = smax(sc[ct], lim, masked);
        }
        __builtin_amdgcn_s_setprio(1);
#pragma unroll
        for (int dt = 0; dt < 4; ++dt) {
            const int d = dt * 16 + lr;
#pragma unroll
            for (int ct = 0; ct < 4; ++ct) {
                short4v vf = *(const short4v*)
                    &vb[d * 64 + ((((ct << 1) + (lq >> 1)) ^ (lr & 7)) << 3) +
                        (((lq ^ (lr >> 3)) & 1) << 2)];
                of[dt] = mfma_k16(vf, pk[ct], of[dt]);
            }
        }
        __builtin_amdgcn_s_setprio(0);
    };

    for (int t = 0; t < ntl; ++t) {
        __syncthreads();          // WAR: prior tile's LDS reads complete
        stageKV();
        __syncthreads();          // staged data visible
        tile(jb + t);
    }

    float l = ls.x + ls.y;
    l += __shfl_xor(l, 16);
    l += __shfl_xor(l, 32);
    // write UNNORMALIZED partial O (bf16, n-major) + partial l (one per row)
#pragma unroll
    for (int dt = 0; dt < 4; ++dt) {
        u16 o[4];
#pragma unroll
        for (int r = 0; r < 4; ++r) o[r] = f2b(of[dt][r]);
        *(ushort4*)&Op[(size_t)irow * 64 + dt * 16 + lq * 4] = *(ushort4*)o;
    }
    if (lq == 0) Lsel[irow] = l;
}

// ---------------- combine splits+groups (n-major partials):
// AO[b,n,hh*64+d] = (Oa0+Ob0)/(la0+lb0) + (Oa1+Ob1)/(la1+lb1)
// grid-stride x2, fully coalesced, no LDS ----------------
__global__ __launch_bounds__(256) void k_gsum(const u16* __restrict__ O,
                                              const float* __restrict__ Lp,
                                              u16* __restrict__ AO) {
#pragma unroll
    for (int it = 0; it < 2; ++it) {
        const int idx = blockIdx.x * 256 + threadIdx.x + it * 131072;  // 8B chunk id
        const int c8 = idx & 63;
        const int n = (idx >> 6) & 2047;
        const int b = idx >> 17;
        const int hh = c8 >> 3;
        const int ch = c8 & 7;
        const int q0 = b * QHH + 2 * hh, q1 = q0 + 1;
        const size_t SOFF = (size_t)BB * QHH * NN * 64;   // s=1 O offset (u16 units)
        const size_t LOFF = (size_t)BB * QHH * NN;        // s=1 L offset (floats)
        const u16* a0 = O + ((size_t)q0 * NN + n) * 64 + ch * 8;
        const u16* a1 = O + ((size_t)q1 * NN + n) * 64 + ch * 8;
        const u16* b0 = a0 + SOFF;
        const u16* b1 = a1 + SOFF;
        const float l0 = Lp[(size_t)q0 * NN + n] + Lp[LOFF + (size_t)q0 * NN + n];
        const float l1 = Lp[(size_t)q1 * NN + n] + Lp[LOFF + (size_t)q1 * NN + n];
        const float inv0 = fastrcp(l0);
        const float inv1 = fastrcp(l1);
        short8 va0 = *(const short8*)a0;
        short8 vb0 = *(const short8*)b0;
        short8 va1 = *(const short8*)a1;
        short8 vb1 = *(const short8*)b1;
        u16 o[8];
#pragma unroll
        for (int jx = 0; jx < 8; ++jx)
            o[jx] = f2b((b2f((u16)va0[jx]) + b2f((u16)vb0[jx])) * inv0 +
                        (b2f((u16)va1[jx]) + b2f((u16)vb1[jx])) * inv1);
        *(short8*)&AO[((size_t)(b * NN + n)) * 512 + c8 * 8] = *(short8*)o;
    }
}

extern "C" void kernel_launch(void* const* d_in, const int* in_sizes, int n_in,
                              void* d_out, int out_size, void* d_ws, size_t ws_size,
                              hipStream_t stream) {
    const float* tokens = (const float*)d_in[0];
    const float* norm_w = (const float*)d_in[1];
    const float* Wq = (const float*)d_in[2];
    const float* Wkv = (const float*)d_in[3];
    const float* Wout = (const float*)d_in[4];
    const float* q_gamma = (const float*)d_in[5];
    const float* k_gamma = (const float*)d_in[6];
    float* out = (float*)d_out;

    char* ws = (char*)d_ws;
    u16* xb = (u16*)(ws + 0);             // 8 MB  [4096,1024]
    u16* WqT = (u16*)(ws + 8388608);      // 2 MB  } adjacent => fused Bt [2048][1024]
    u16* WkvT = (u16*)(ws + 10485760);    // 2 MB  }
    u16* WoutT = (u16*)(ws + 12582912);   // 1 MB
    u16* kn = (u16*)(ws + 30408704);      // 4 MB
    u16* vtb = (u16*)(ws + 34603008);     // 4 MB
    u16* qn = (u16*)(ws + 38797312);      // 8 MB (fresh: gemm128 writes while reading xb)
    // Lifetime aliases (stream-ordered, no overlap):
    u16* Opart = (u16*)(ws + 13631488);   // 16 MB attn partials (2 splits x 8 MB)
    float* Lpart = (float*)(ws + 8388608);  // 512 KB in WqT/WkvT region (dead after gemm128)
    u16* AO = kn;                         // 4 MB: kn dead after attn; AO written by gsum

    k_pre<<<7168, 256, 0, stream>>>(tokens, norm_w, xb, Wq, Wkv, Wout, WqT, WkvT, WoutT);
    // fused QKV GEMM + headnorm/V-transpose epilogue (k_mid eliminated)
    k_gemm128<<<dim3(16, 32), 256, 0, stream>>>(xb, WqT, q_gamma, k_gamma, qn, kn, vtb, 1024);
    k_attn<<<dim3(32, 64), 256, 0, stream>>>(qn, kn, vtb, Opart, Lpart);
    k_gsum<<<512, 256, 0, stream>>>(Opart, Lpart, AO);
    k_gemm64f<<<dim3(8, 64), 256, 0, stream>>>(AO, WoutT, out, 4096, 1024, 512);
}